// Round 2
// baseline (7714.091 us; speedup 1.0000x reference)
//
#include <hip/hip_runtime.h>

#define N 4096
#define B 8
#define ITERS 10
#define T (ITERS * N)
#define NT 256          // 4 waves
#define E 16            // field elements per thread
#define WIN 1024
#define INFK 0xFFFFFFFFu
#define LIMIT 0x01000000u

// LDS-only barrier: inner-loop cross-wave traffic is LDS slots only, so
// lgkmcnt(0) suffices; in-flight global row loads stay in flight.
// Parity-buffered slots + 1 barrier/round is race-free (2 buffers, every
// reuse separated by >= 2 barriers).
__device__ __forceinline__ void lds_barrier() {
    asm volatile("s_waitcnt lgkmcnt(0)\n\ts_barrier" ::: "memory");
}

// Kernel 1: Z0[b][i] = sum_j W[i][j] * x[b][j], accumulated in double.
__global__ __launch_bounds__(256) void z0_gemv(const float* __restrict__ W,
                                               const float* __restrict__ x,
                                               double* __restrict__ Z0) {
    const int i = blockIdx.x;
    const int tid = threadIdx.x;
    const int lane = tid & 63;
    const int wid = tid >> 6;
    const float4* __restrict__ row = (const float4*)(W + (size_t)i * N);
    const float4* __restrict__ xv = (const float4*)x;

    double acc[B];
#pragma unroll
    for (int b = 0; b < B; ++b) acc[b] = 0.0;

#pragma unroll
    for (int it = 0; it < 4; ++it) {
        const int c = tid + 256 * it;
        const float4 w = row[c];
#pragma unroll
        for (int b = 0; b < B; ++b) {
            const float4 xb = xv[b * (N / 4) + c];
            acc[b] += (double)w.x * (double)xb.x + (double)w.y * (double)xb.y +
                      (double)w.z * (double)xb.z + (double)w.w * (double)xb.w;
        }
    }

#pragma unroll
    for (int off = 32; off > 0; off >>= 1) {
#pragma unroll
        for (int b = 0; b < B; ++b) acc[b] += __shfl_down(acc[b], off, 64);
    }

    __shared__ double red[4][B];
    if (lane == 0) {
#pragma unroll
        for (int b = 0; b < B; ++b) red[wid][b] = acc[b];
    }
    __syncthreads();
    if (tid < B)
        Z0[(size_t)tid * N + i] = red[0][tid] + red[1][tid] + red[2][tid] + red[3][tid];
}

__device__ __forceinline__ unsigned umin2(unsigned a, unsigned b) { return a < b ? a : b; }

template <int CTRL>
__device__ __forceinline__ unsigned dpp_min(unsigned v) {
    const int t = __builtin_amdgcn_update_dpp((int)v, (int)v, CTRL, 0xF, 0xF, false);
    return umin2(v, (unsigned)t);
}

// Full wave64 min via DPP; wave-uniform result via readlane(63).
__device__ __forceinline__ unsigned wave_min64(unsigned v) {
    v = dpp_min<0x111>(v);  // row_shr:1
    v = dpp_min<0x112>(v);  // row_shr:2
    v = dpp_min<0x114>(v);  // row_shr:4
    v = dpp_min<0x118>(v);  // row_shr:8
    v = dpp_min<0x142>(v);  // row_bcast:15
    v = dpp_min<0x143>(v);  // row_bcast:31
    return (unsigned)__builtin_amdgcn_readlane((int)v, 63);
}

// Kernel 2: pairwise-speculative register-resident scan.
// Per round, speculatively apply the current top-2 candidates (i1, i2):
//   mid  = state after i1 only  (scan under ck1, i1's owner flipped)
//   post = state after i1 & i2  (scan under ck2, both owners flipped)
// Publish per-wave top-2 of BOTH states; ONE barrier; resolve exactly:
//   success <=> global mid-min == i2's mid-key (no interloper in (pos1,pos2),
//               i2 still mismatched)  -> commit 2 flips, next pair = post top2.
//   failure -> roll back to saved zm[] (bit-exact), unflip i2, next pair =
//              mid top2 (the true next winner -- no wasted round).
// Key algebra unchanged: sk = pos<<14 | i<<2 | (y+1); cand = (sk|match)-ck.
__global__ __launch_bounds__(256) void hop_seq(const float* __restrict__ W,
                                               const float* __restrict__ x,
                                               const int* __restrict__ perms,
                                               const double* __restrict__ Z0,
                                               float* __restrict__ out) {
    const int b = blockIdx.x;
    const int tid = threadIdx.x;
    const int wid = tid >> 6;
    const int lane = tid & 63;

    __shared__ int wpos[N];        // 16 KB epoch-tagged inverse map
    __shared__ uint4 sM1[2], sM2[2], sP1[2], sP2[2];  // parity-buffered slots

    // ---- register-resident field ----
    double zj[E];
    unsigned ymask[E];             // 0xFFFFFFFF if y>0 else 0x7FFFFFFF
    unsigned sk[E];
    {
        const double* __restrict__ zsrc = Z0 + (size_t)b * N + E * tid;
#pragma unroll
        for (int k = 0; k < E; ++k) zj[k] = zsrc[k];
        const float4* __restrict__ xs = (const float4*)(x + (size_t)b * N);
#pragma unroll
        for (int q = 0; q < 4; ++q) {
            const float4 xv = xs[4 * tid + q];
            ymask[4 * q + 0] = (xv.x > 0.f) ? 0xFFFFFFFFu : 0x7FFFFFFFu;
            ymask[4 * q + 1] = (xv.y > 0.f) ? 0xFFFFFFFFu : 0x7FFFFFFFu;
            ymask[4 * q + 2] = (xv.z > 0.f) ? 0xFFFFFFFFu : 0x7FFFFFFFu;
            ymask[4 * q + 3] = (xv.w > 0.f) ? 0xFFFFFFFFu : 0x7FFFFFFFu;
        }
    }
    const int* __restrict__ perm_b = perms + (size_t)b * T;

    float w1[E], w2[E];            // pair rows, register-resident
    int t1i = -1, t2i = -1;        // which row index each buffer holds
    unsigned r = 0;                // barrier parity counter

    // Fetch pair rows with reuse of whatever w1/w2 already hold.
    auto fetch_pair = [&](int ni1, int ni2) {
        float a1[E], a2[E];
        if (ni1 == t1i) {
#pragma unroll
            for (int k = 0; k < E; ++k) a1[k] = w1[k];
        } else if (ni1 == t2i) {
#pragma unroll
            for (int k = 0; k < E; ++k) a1[k] = w2[k];
        } else {
            const float4* __restrict__ rp = (const float4*)(W + (size_t)ni1 * N) + 4 * tid;
            const float4 A = rp[0], C = rp[1], Dv = rp[2], F = rp[3];
            a1[0] = A.x;  a1[1] = A.y;  a1[2] = A.z;  a1[3] = A.w;
            a1[4] = C.x;  a1[5] = C.y;  a1[6] = C.z;  a1[7] = C.w;
            a1[8] = Dv.x; a1[9] = Dv.y; a1[10] = Dv.z; a1[11] = Dv.w;
            a1[12] = F.x; a1[13] = F.y; a1[14] = F.z; a1[15] = F.w;
        }
        if (ni2 >= 0) {
            if (ni2 == t1i) {
#pragma unroll
                for (int k = 0; k < E; ++k) a2[k] = w1[k];
            } else if (ni2 == t2i) {
#pragma unroll
                for (int k = 0; k < E; ++k) a2[k] = w2[k];
            } else {
                const float4* __restrict__ rp = (const float4*)(W + (size_t)ni2 * N) + 4 * tid;
                const float4 A = rp[0], C = rp[1], Dv = rp[2], F = rp[3];
                a2[0] = A.x;  a2[1] = A.y;  a2[2] = A.z;  a2[3] = A.w;
                a2[4] = C.x;  a2[5] = C.y;  a2[6] = C.z;  a2[7] = C.w;
                a2[8] = Dv.x; a2[9] = Dv.y; a2[10] = Dv.z; a2[11] = Dv.w;
                a2[12] = F.x; a2[13] = F.y; a2[14] = F.z; a2[15] = F.w;
            }
        }
#pragma unroll
        for (int k = 0; k < E; ++k) w1[k] = a1[k];
        t1i = ni1;
        if (ni2 >= 0) {
#pragma unroll
            for (int k = 0; k < E; ++k) w2[k] = a2[k];
            t2i = ni2;
        }
    };

    for (int base = 0; base < T; base += WIN) {
        const int epoch = (base >> 10) + 1;
        // scatter inverse map (window = permutation slice, indices distinct)
        const int4 iv = ((const int4*)(perm_b + base))[tid];
        wpos[iv.x] = (epoch << 10) | (4 * tid + 0);
        wpos[iv.y] = (epoch << 10) | (4 * tid + 1);
        wpos[iv.z] = (epoch << 10) | (4 * tid + 2);
        wpos[iv.w] = (epoch << 10) | (4 * tid + 3);
        lds_barrier();
        // build static keys for the 16 owned elems
#pragma unroll
        for (int q = 0; q < 4; ++q) {
            const int4 wp = ((const int4*)wpos)[4 * tid + q];
            const int e0 = 4 * q;
            const unsigned i0 = (unsigned)(E * tid + e0);
            sk[e0 + 0] = ((wp.x >> 10) == epoch)
                ? (((unsigned)(wp.x & 1023) << 14) | ((i0 + 0) << 2) | ((ymask[e0 + 0] >> 30) & 2u)) : INFK;
            sk[e0 + 1] = ((wp.y >> 10) == epoch)
                ? (((unsigned)(wp.y & 1023) << 14) | ((i0 + 1) << 2) | ((ymask[e0 + 1] >> 30) & 2u)) : INFK;
            sk[e0 + 2] = ((wp.z >> 10) == epoch)
                ? (((unsigned)(wp.z & 1023) << 14) | ((i0 + 2) << 2) | ((ymask[e0 + 2] >> 30) & 2u)) : INFK;
            sk[e0 + 3] = ((wp.w >> 10) == epoch)
                ? (((unsigned)(wp.w & 1023) << 14) | ((i0 + 3) << 2) | ((ymask[e0 + 3] >> 30) & 2u)) : INFK;
        }

        // ---- round-0: top-2 of fresh window state (ck = 0) ----
        unsigned key = INFK;
#pragma unroll
        for (int k = 0; k < E; ++k) {
            const unsigned t2v = ((unsigned)__double2hiint(zj[k])) ^ ymask[k];
            key = umin2(key, sk[k] | (unsigned)(((int)t2v) >> 31));
        }
        unsigned wk1, wk2;
        bool valid2;
        {
            const unsigned m1 = wave_min64(key);
            const unsigned m2 = wave_min64(key == m1 ? INFK : key);
            const unsigned p = r & 1u; ++r;
            if (lane == 0) { ((unsigned*)&sP1[p])[wid] = m1; ((unsigned*)&sP2[p])[wid] = m2; }
            lds_barrier();
            const uint4 s1 = sP1[p];
            const unsigned g = umin2(umin2(s1.x, s1.y), umin2(s1.z, s1.w));
            if (g >= LIMIT) continue;      // window already converged
            const uint4 s2 = sP2[p];
            const unsigned o0 = (s1.x == g) ? s2.x : s1.x;
            const unsigned o1 = (s1.y == g) ? s2.y : s1.y;
            const unsigned o2 = (s1.z == g) ? s2.z : s1.z;
            const unsigned o3 = (s1.w == g) ? s2.w : s1.w;
            const unsigned g2 = umin2(umin2(o0, o1), umin2(o2, o3));
            wk1 = g; wk2 = g2; valid2 = g2 < LIMIT;
        }
        fetch_pair((int)((wk1 >> 2) & 4095u), valid2 ? (int)((wk2 >> 2) & 4095u) : -1);

        for (;;) {
            const unsigned ck1 = ((wk1 >> 14) + 1u) << 14;
            const int i1 = (int)((wk1 >> 2) & 4095u);
            const double d1 = (double)(-2 * ((int)(wk1 & 3u) - 1));
            if (tid == (i1 >> 4)) {
                const int kk = i1 & 15;
#pragma unroll
                for (int k = 0; k < E; ++k)
                    if (k == kk) { ymask[k] ^= 0x80000000u; sk[k] ^= 2u; }
            }
            // ---- mid: apply i1, scan under ck1 (zm kept for exact rollback) ----
            double zm[E];
            unsigned keyM = INFK;
#pragma unroll
            for (int k = 0; k < E; ++k) {
                zm[k] = zj[k] + d1 * (double)w1[k];   // W[i1][i1]==0 -> owner safe
                const unsigned t2v = ((unsigned)__double2hiint(zm[k])) ^ ymask[k];
                keyM = umin2(keyM, (sk[k] | (unsigned)(((int)t2v) >> 31)) - ck1);
            }
            unsigned mm1 = INFK, mm2 = INFK, pm1, pm2;
            unsigned ck2 = ck1, target = 0;
            int i2 = -1;
            if (valid2) {
                i2 = (int)((wk2 >> 2) & 4095u);
                const double d2 = (double)(-2 * ((int)(wk2 & 3u) - 1));
                ck2 = ((wk2 >> 14) + 1u) << 14;
                target = wk2 - ck1;       // i2's key as seen by the mid scan
                mm1 = wave_min64(keyM);
                mm2 = wave_min64(keyM == mm1 ? INFK : keyM);
                if (tid == (i2 >> 4)) {
                    const int kk = i2 & 15;
#pragma unroll
                    for (int k = 0; k < E; ++k)
                        if (k == kk) { ymask[k] ^= 0x80000000u; sk[k] ^= 2u; }
                }
                // ---- post: apply i2, scan under ck2 ----
                unsigned keyP = INFK;
#pragma unroll
                for (int k = 0; k < E; ++k) {
                    zj[k] = zm[k] + d2 * (double)w2[k];
                    const unsigned t2v = ((unsigned)__double2hiint(zj[k])) ^ ymask[k];
                    keyP = umin2(keyP, (sk[k] | (unsigned)(((int)t2v) >> 31)) - ck2);
                }
                pm1 = wave_min64(keyP);
                pm2 = wave_min64(keyP == pm1 ? INFK : keyP);
            } else {
                // single-candidate round: post == mid
#pragma unroll
                for (int k = 0; k < E; ++k) zj[k] = zm[k];
                pm1 = wave_min64(keyM);
                pm2 = wave_min64(keyM == pm1 ? INFK : keyM);
            }
            // ---- publish both states' top-2, ONE barrier ----
            const unsigned p = r & 1u; ++r;
            if (lane == 0) {
                ((unsigned*)&sM1[p])[wid] = mm1;
                ((unsigned*)&sM2[p])[wid] = mm2;
                ((unsigned*)&sP1[p])[wid] = pm1;
                ((unsigned*)&sP2[p])[wid] = pm2;
            }
            lds_barrier();
            const uint4 q1 = sP1[p];
            const unsigned gp = umin2(umin2(q1.x, q1.y), umin2(q1.z, q1.w));
            const uint4 q2 = sP2[p];
            const unsigned po0 = (q1.x == gp) ? q2.x : q1.x;
            const unsigned po1 = (q1.y == gp) ? q2.y : q1.y;
            const unsigned po2 = (q1.z == gp) ? q2.z : q1.z;
            const unsigned po3 = (q1.w == gp) ? q2.w : q1.w;
            const unsigned gp2 = umin2(umin2(po0, po1), umin2(po2, po3));
            bool success = true;
            unsigned gm = INFK, gm2 = INFK;
            if (valid2) {
                const uint4 u1 = sM1[p];
                gm = umin2(umin2(u1.x, u1.y), umin2(u1.z, u1.w));
                const uint4 u2 = sM2[p];
                const unsigned mo0 = (u1.x == gm) ? u2.x : u1.x;
                const unsigned mo1 = (u1.y == gm) ? u2.y : u1.y;
                const unsigned mo2 = (u1.z == gm) ? u2.z : u1.z;
                const unsigned mo3 = (u1.w == gm) ? u2.w : u1.w;
                gm2 = umin2(umin2(mo0, mo1), umin2(mo2, mo3));
                success = (gm == target);
            }
            if (success) {
                if (gp >= LIMIT) break;   // window complete, state stands
                wk1 = gp + ck2;
                valid2 = gp2 < LIMIT;
                wk2 = valid2 ? gp2 + ck2 : INFK;
                fetch_pair((int)((wk1 >> 2) & 4095u), valid2 ? (int)((wk2 >> 2) & 4095u) : -1);
            } else {
                const bool done = (gm >= LIMIT);
                const unsigned nwk1 = gm + ck1;
                const bool nv2 = gm2 < LIMIT;
                const unsigned nwk2 = nv2 ? gm2 + ck1 : INFK;
                if (!done)  // issue next loads before rollback VALU work
                    fetch_pair((int)((nwk1 >> 2) & 4095u), nv2 ? (int)((nwk2 >> 2) & 4095u) : -1);
                // ---- exact rollback to mid ----
#pragma unroll
                for (int k = 0; k < E; ++k) zj[k] = zm[k];
                if (tid == (i2 >> 4)) {
                    const int kk = i2 & 15;
#pragma unroll
                    for (int k = 0; k < E; ++k)
                        if (k == kk) { ymask[k] ^= 0x80000000u; sk[k] ^= 2u; }
                }
                if (done) break;
                wk1 = nwk1; wk2 = nwk2; valid2 = nv2;
            }
        }
    }

    // ---- output: y = +1 if ymask top bit set else -1 ----
    float4* __restrict__ os = (float4*)(out + (size_t)b * N);
#pragma unroll
    for (int q = 0; q < 4; ++q) {
        float4 o;
        o.x = (ymask[4 * q + 0] & 0x80000000u) ? 1.0f : -1.0f;
        o.y = (ymask[4 * q + 1] & 0x80000000u) ? 1.0f : -1.0f;
        o.z = (ymask[4 * q + 2] & 0x80000000u) ? 1.0f : -1.0f;
        o.w = (ymask[4 * q + 3] & 0x80000000u) ? 1.0f : -1.0f;
        os[4 * tid + q] = o;
    }
}

extern "C" void kernel_launch(void* const* d_in, const int* in_sizes, int n_in,
                              void* d_out, int out_size, void* d_ws, size_t ws_size,
                              hipStream_t stream) {
    const float* x = (const float*)d_in[0];      // [B, N] f32, bipolar
    const float* W = (const float*)d_in[1];      // [N, N] f32, symmetric, zero diag
    const int* perms = (const int*)d_in[2];      // [B, ITERS, N] i32
    float* out = (float*)d_out;                  // [B, N] f32
    double* Z0 = (double*)d_ws;                  // B*N doubles = 256 KB scratch

    hipLaunchKernelGGL(z0_gemv, dim3(N), dim3(256), 0, stream, W, x, Z0);
    hipLaunchKernelGGL(hop_seq, dim3(B), dim3(NT), 0, stream, W, x, perms, Z0, out);
}

// Round 3
// 4651.400 us; speedup vs baseline: 1.6584x; 1.6584x over previous
//
#include <hip/hip_runtime.h>

#define N 4096
#define B 8
#define ITERS 10
#define T (ITERS * N)
#define NT 256          // 4 waves
#define E 16            // field elements per thread per sample
#define WIN 1024
#define INFK 0xFFFFFFFFu
#define LIMIT 0x01000000u

// LDS-only barrier: inner-loop cross-wave traffic is LDS slots only, so
// lgkmcnt(0) suffices. Parity-buffered slots + 1 barrier/iter is race-free.
__device__ __forceinline__ void lds_barrier() {
    asm volatile("s_waitcnt lgkmcnt(0)\n\ts_barrier" ::: "memory");
}

// Kernel 1: Z0[b][i] = sum_j W[i][j] * x[b][j], accumulated in double.
__global__ __launch_bounds__(256) void z0_gemv(const float* __restrict__ W,
                                               const float* __restrict__ x,
                                               double* __restrict__ Z0) {
    const int i = blockIdx.x;
    const int tid = threadIdx.x;
    const int lane = tid & 63;
    const int wid = tid >> 6;
    const float4* __restrict__ row = (const float4*)(W + (size_t)i * N);
    const float4* __restrict__ xv = (const float4*)x;

    double acc[B];
#pragma unroll
    for (int b = 0; b < B; ++b) acc[b] = 0.0;

#pragma unroll
    for (int it = 0; it < 4; ++it) {
        const int c = tid + 256 * it;
        const float4 w = row[c];
#pragma unroll
        for (int b = 0; b < B; ++b) {
            const float4 xb = xv[b * (N / 4) + c];
            acc[b] += (double)w.x * (double)xb.x + (double)w.y * (double)xb.y +
                      (double)w.z * (double)xb.z + (double)w.w * (double)xb.w;
        }
    }

#pragma unroll
    for (int off = 32; off > 0; off >>= 1) {
#pragma unroll
        for (int b = 0; b < B; ++b) acc[b] += __shfl_down(acc[b], off, 64);
    }

    __shared__ double red[4][B];
    if (lane == 0) {
#pragma unroll
        for (int b = 0; b < B; ++b) red[wid][b] = acc[b];
    }
    __syncthreads();
    if (tid < B)
        Z0[(size_t)tid * N + i] = red[0][tid] + red[1][tid] + red[2][tid] + red[3][tid];
}

__device__ __forceinline__ unsigned umin2(unsigned a, unsigned b) { return a < b ? a : b; }

template <int CTRL>
__device__ __forceinline__ unsigned dpp_min(unsigned v) {
    const int t = __builtin_amdgcn_update_dpp((int)v, (int)v, CTRL, 0xF, 0xF, false);
    return umin2(v, (unsigned)t);
}

// Full wave64 min via DPP; wave-uniform result via readlane(63).
__device__ __forceinline__ unsigned wave_min64(unsigned v) {
    v = dpp_min<0x111>(v);  // row_shr:1
    v = dpp_min<0x112>(v);  // row_shr:2
    v = dpp_min<0x114>(v);  // row_shr:4
    v = dpp_min<0x118>(v);  // row_shr:8
    v = dpp_min<0x142>(v);  // row_bcast:15
    v = dpp_min<0x143>(v);  // row_bcast:31
    return (unsigned)__builtin_amdgcn_readlane((int)v, 63);
}

// Kernel 2: TWO independent sample chains per block, instruction-interleaved.
// Per iteration (one flip per active chain): publish both chains' per-wave
// mins -> ONE barrier -> decode both winners -> issue BOTH row loads ->
// scan chain B (its load exposed) -> scan chain A (load covered by scan B).
// Halves the per-flip barrier/LDS/decode cost and covers ~half the row-load
// latency. Speculation/prefetch machinery removed (measured ~23% hit rate).
// Key algebra unchanged: sk = pos<<14 | i<<2 | (y+1); per elem per round:
//  zj += d*w; t2 = hi64(zj) ^ ymask; cand = (sk | (t2>>31)) - ck; min.
__global__ __launch_bounds__(256) void hop_seq(const float* __restrict__ W,
                                               const float* __restrict__ x,
                                               const int* __restrict__ perms,
                                               const double* __restrict__ Z0,
                                               float* __restrict__ out) {
    const int pair = blockIdx.x;           // 0..3
    const int sA = 2 * pair, sB = 2 * pair + 1;
    const int tid = threadIdx.x;
    const int wid = tid >> 6;
    const int lane = tid & 63;

    __shared__ int wposA[N], wposB[N];     // 2 x 16 KB epoch-tagged inverse maps
    __shared__ uint4 slotA[2], slotB[2];   // per-wave min, parity buffered

    // ---- register-resident fields, both samples ----
    double zjA[E], zjB[E];
    unsigned ymA[E], ymB[E], skA[E], skB[E];
    {
        const double* __restrict__ za = Z0 + (size_t)sA * N + E * tid;
        const double* __restrict__ zb = Z0 + (size_t)sB * N + E * tid;
#pragma unroll
        for (int k = 0; k < E; ++k) { zjA[k] = za[k]; zjB[k] = zb[k]; }
        const float4* __restrict__ xa = (const float4*)(x + (size_t)sA * N);
        const float4* __restrict__ xb = (const float4*)(x + (size_t)sB * N);
#pragma unroll
        for (int q = 0; q < 4; ++q) {
            const float4 va = xa[4 * tid + q];
            const float4 vb = xb[4 * tid + q];
            ymA[4 * q + 0] = (va.x > 0.f) ? 0xFFFFFFFFu : 0x7FFFFFFFu;
            ymA[4 * q + 1] = (va.y > 0.f) ? 0xFFFFFFFFu : 0x7FFFFFFFu;
            ymA[4 * q + 2] = (va.z > 0.f) ? 0xFFFFFFFFu : 0x7FFFFFFFu;
            ymA[4 * q + 3] = (va.w > 0.f) ? 0xFFFFFFFFu : 0x7FFFFFFFu;
            ymB[4 * q + 0] = (vb.x > 0.f) ? 0xFFFFFFFFu : 0x7FFFFFFFu;
            ymB[4 * q + 1] = (vb.y > 0.f) ? 0xFFFFFFFFu : 0x7FFFFFFFu;
            ymB[4 * q + 2] = (vb.z > 0.f) ? 0xFFFFFFFFu : 0x7FFFFFFFu;
            ymB[4 * q + 3] = (vb.w > 0.f) ? 0xFFFFFFFFu : 0x7FFFFFFFu;
        }
    }
    // zero-init inverse maps (window-1 stale-tag hazard: LDS is undefined)
    {
        const int4 z4 = make_int4(0, 0, 0, 0);
#pragma unroll
        for (int q = 0; q < 4; ++q) {
            ((int4*)wposA)[tid + 256 * q] = z4;
            ((int4*)wposB)[tid + 256 * q] = z4;
        }
    }
    lds_barrier();

    const int* __restrict__ permA = perms + (size_t)sA * T;
    const int* __restrict__ permB = perms + (size_t)sB * T;
    unsigned r = 0;                        // barrier parity counter

    for (int base = 0; base < T; base += WIN) {
        const int epoch = (base >> 10) + 1;
        // scatter inverse maps (window = permutation slice, indices distinct)
        const int4 ia = ((const int4*)(permA + base))[tid];
        const int4 ib = ((const int4*)(permB + base))[tid];
        wposA[ia.x] = (epoch << 10) | (4 * tid + 0);
        wposA[ia.y] = (epoch << 10) | (4 * tid + 1);
        wposA[ia.z] = (epoch << 10) | (4 * tid + 2);
        wposA[ia.w] = (epoch << 10) | (4 * tid + 3);
        wposB[ib.x] = (epoch << 10) | (4 * tid + 0);
        wposB[ib.y] = (epoch << 10) | (4 * tid + 1);
        wposB[ib.z] = (epoch << 10) | (4 * tid + 2);
        wposB[ib.w] = (epoch << 10) | (4 * tid + 3);
        lds_barrier();
        // build static keys for the 16 owned elems of each sample
#pragma unroll
        for (int q = 0; q < 4; ++q) {
            const int4 wa = ((const int4*)wposA)[4 * tid + q];
            const int4 wb = ((const int4*)wposB)[4 * tid + q];
            const int e0 = 4 * q;
            const unsigned i0 = (unsigned)(E * tid + e0);
            skA[e0 + 0] = ((wa.x >> 10) == epoch)
                ? (((unsigned)(wa.x & 1023) << 14) | ((i0 + 0) << 2) | ((ymA[e0 + 0] >> 30) & 2u)) : INFK;
            skA[e0 + 1] = ((wa.y >> 10) == epoch)
                ? (((unsigned)(wa.y & 1023) << 14) | ((i0 + 1) << 2) | ((ymA[e0 + 1] >> 30) & 2u)) : INFK;
            skA[e0 + 2] = ((wa.z >> 10) == epoch)
                ? (((unsigned)(wa.z & 1023) << 14) | ((i0 + 2) << 2) | ((ymA[e0 + 2] >> 30) & 2u)) : INFK;
            skA[e0 + 3] = ((wa.w >> 10) == epoch)
                ? (((unsigned)(wa.w & 1023) << 14) | ((i0 + 3) << 2) | ((ymA[e0 + 3] >> 30) & 2u)) : INFK;
            skB[e0 + 0] = ((wb.x >> 10) == epoch)
                ? (((unsigned)(wb.x & 1023) << 14) | ((i0 + 0) << 2) | ((ymB[e0 + 0] >> 30) & 2u)) : INFK;
            skB[e0 + 1] = ((wb.y >> 10) == epoch)
                ? (((unsigned)(wb.y & 1023) << 14) | ((i0 + 1) << 2) | ((ymB[e0 + 1] >> 30) & 2u)) : INFK;
            skB[e0 + 2] = ((wb.z >> 10) == epoch)
                ? (((unsigned)(wb.z & 1023) << 14) | ((i0 + 2) << 2) | ((ymB[e0 + 2] >> 30) & 2u)) : INFK;
            skB[e0 + 3] = ((wb.w >> 10) == epoch)
                ? (((unsigned)(wb.w & 1023) << 14) | ((i0 + 3) << 2) | ((ymB[e0 + 3] >> 30) & 2u)) : INFK;
        }

        unsigned ckA = 0, ckB = 0;
        bool doneA = false, doneB = false;
        // round-0 pure scans (ck = 0)
        unsigned keyA = INFK, keyB = INFK;
#pragma unroll
        for (int k = 0; k < E; ++k) {
            const unsigned ta = ((unsigned)__double2hiint(zjA[k])) ^ ymA[k];
            keyA = umin2(keyA, skA[k] | (unsigned)(((int)ta) >> 31));
            const unsigned tb = ((unsigned)__double2hiint(zjB[k])) ^ ymB[k];
            keyB = umin2(keyB, skB[k] | (unsigned)(((int)tb) >> 31));
        }

        for (;;) {
            const unsigned mA = doneA ? INFK : wave_min64(keyA);
            const unsigned mB = doneB ? INFK : wave_min64(keyB);
            const unsigned p = r & 1u; ++r;
            if (lane == 0) {
                ((unsigned*)&slotA[p])[wid] = mA;
                ((unsigned*)&slotB[p])[wid] = mB;
            }
            lds_barrier();
            const uint4 a4 = slotA[p];
            const uint4 b4 = slotB[p];
            const unsigned gA = umin2(umin2(a4.x, a4.y), umin2(a4.z, a4.w));
            const unsigned gB = umin2(umin2(b4.x, b4.y), umin2(b4.z, b4.w));
            const bool fA = (!doneA) && (gA < LIMIT);   // uniform
            const bool fB = (!doneB) && (gB < LIMIT);   // uniform
            if (!fA && !fB) break;

            // ---- decode winners, issue BOTH row loads ASAP ----
            float wrA[E], wrB[E];
            unsigned wkA = 0, wkB = 0;
            int iA = 0, iB = 0;
            if (fB) {
                wkB = gB + ckB;
                iB = (int)((wkB >> 2) & 4095u);
                const float4* __restrict__ rp = (const float4*)(W + (size_t)iB * N) + 4 * tid;
                const float4 A0 = rp[0], A1 = rp[1], A2 = rp[2], A3 = rp[3];
                wrB[0] = A0.x;  wrB[1] = A0.y;  wrB[2] = A0.z;  wrB[3] = A0.w;
                wrB[4] = A1.x;  wrB[5] = A1.y;  wrB[6] = A1.z;  wrB[7] = A1.w;
                wrB[8] = A2.x;  wrB[9] = A2.y;  wrB[10] = A2.z; wrB[11] = A2.w;
                wrB[12] = A3.x; wrB[13] = A3.y; wrB[14] = A3.z; wrB[15] = A3.w;
            }
            if (fA) {
                wkA = gA + ckA;
                iA = (int)((wkA >> 2) & 4095u);
                const float4* __restrict__ rp = (const float4*)(W + (size_t)iA * N) + 4 * tid;
                const float4 A0 = rp[0], A1 = rp[1], A2 = rp[2], A3 = rp[3];
                wrA[0] = A0.x;  wrA[1] = A0.y;  wrA[2] = A0.z;  wrA[3] = A0.w;
                wrA[4] = A1.x;  wrA[5] = A1.y;  wrA[6] = A1.z;  wrA[7] = A1.w;
                wrA[8] = A2.x;  wrA[9] = A2.y;  wrA[10] = A2.z; wrA[11] = A2.w;
                wrA[12] = A3.x; wrA[13] = A3.y; wrA[14] = A3.z; wrA[15] = A3.w;
            }

            // ---- owner fixups + ck advances ----
            double dB = 0.0, dA = 0.0;
            if (fB) {
                dB = (double)(-2 * ((int)(wkB & 3u) - 1));
                ckB = ((wkB >> 14) + 1u) << 14;
                if (tid == (iB >> 4)) {
                    const int kk = iB & 15;
#pragma unroll
                    for (int k = 0; k < E; ++k)
                        if (k == kk) { ymB[k] ^= 0x80000000u; skB[k] ^= 2u; }
                }
            }
            if (fA) {
                dA = (double)(-2 * ((int)(wkA & 3u) - 1));
                ckA = ((wkA >> 14) + 1u) << 14;
                if (tid == (iA >> 4)) {
                    const int kk = iA & 15;
#pragma unroll
                    for (int k = 0; k < E; ++k)
                        if (k == kk) { ymA[k] ^= 0x80000000u; skA[k] ^= 2u; }
                }
            }

            // ---- fused apply + scan, B first (exposed), A second (covered) ----
            if (fB) {
                keyB = INFK;
#pragma unroll
                for (int k = 0; k < E; ++k) {
                    zjB[k] += dB * (double)wrB[k];   // W[iB][iB]==0 -> owner safe
                    const unsigned t2 = ((unsigned)__double2hiint(zjB[k])) ^ ymB[k];
                    keyB = umin2(keyB, (skB[k] | (unsigned)(((int)t2) >> 31)) - ckB);
                }
            }
            if (fA) {
                keyA = INFK;
#pragma unroll
                for (int k = 0; k < E; ++k) {
                    zjA[k] += dA * (double)wrA[k];   // W[iA][iA]==0 -> owner safe
                    const unsigned t2 = ((unsigned)__double2hiint(zjA[k])) ^ ymA[k];
                    keyA = umin2(keyA, (skA[k] | (unsigned)(((int)t2) >> 31)) - ckA);
                }
            }
            doneA = !fA;
            doneB = !fB;
        }
    }

    // ---- output both samples: y = +1 if ymask top bit set else -1 ----
    float4* __restrict__ oa = (float4*)(out + (size_t)sA * N);
    float4* __restrict__ ob = (float4*)(out + (size_t)sB * N);
#pragma unroll
    for (int q = 0; q < 4; ++q) {
        float4 o;
        o.x = (ymA[4 * q + 0] & 0x80000000u) ? 1.0f : -1.0f;
        o.y = (ymA[4 * q + 1] & 0x80000000u) ? 1.0f : -1.0f;
        o.z = (ymA[4 * q + 2] & 0x80000000u) ? 1.0f : -1.0f;
        o.w = (ymA[4 * q + 3] & 0x80000000u) ? 1.0f : -1.0f;
        oa[4 * tid + q] = o;
        float4 ob4;
        ob4.x = (ymB[4 * q + 0] & 0x80000000u) ? 1.0f : -1.0f;
        ob4.y = (ymB[4 * q + 1] & 0x80000000u) ? 1.0f : -1.0f;
        ob4.z = (ymB[4 * q + 2] & 0x80000000u) ? 1.0f : -1.0f;
        ob4.w = (ymB[4 * q + 3] & 0x80000000u) ? 1.0f : -1.0f;
        ob[4 * tid + q] = ob4;
    }
}

extern "C" void kernel_launch(void* const* d_in, const int* in_sizes, int n_in,
                              void* d_out, int out_size, void* d_ws, size_t ws_size,
                              hipStream_t stream) {
    const float* x = (const float*)d_in[0];      // [B, N] f32, bipolar
    const float* W = (const float*)d_in[1];      // [N, N] f32, symmetric, zero diag
    const int* perms = (const int*)d_in[2];      // [B, ITERS, N] i32
    float* out = (float*)d_out;                  // [B, N] f32
    double* Z0 = (double*)d_ws;                  // B*N doubles = 256 KB scratch

    hipLaunchKernelGGL(z0_gemv, dim3(N), dim3(256), 0, stream, W, x, Z0);
    hipLaunchKernelGGL(hop_seq, dim3(B / 2), dim3(NT), 0, stream, W, x, perms, Z0, out);
}